// Round 1
// baseline (422.286 us; speedup 1.0000x reference)
//
#include <hip/hip_runtime.h>

typedef _Float16 v8h __attribute__((ext_vector_type(8)));
typedef _Float16 v4h __attribute__((ext_vector_type(4)));
typedef float v4f __attribute__((ext_vector_type(4)));

#define NB 64
#define CI 96
#define CE 576
#define CO 96
#define HW 784
#define SEC 144

// ---------------- K0: convert GEMM weights to fp16 (integers +-127, exact) ----
__global__ __launch_bounds__(256) void k0_cvt_w(const float* __restrict__ w_exp,
                                                const float* __restrict__ w_proj,
                                                _Float16* __restrict__ w_exp_h,
                                                _Float16* __restrict__ w_proj_h) {
  int i = blockIdx.x * 256 + threadIdx.x;
  if (i < CE * CI) {                 // 55296 == CE*CI == CO*CE
    w_exp_h[i]  = (_Float16)w_exp[i];
    w_proj_h[i] = (_Float16)w_proj[i];
  }
}

// ---------------- K1: expand 1x1 + hardswish + requant -> e_s fp16 [n][c][hw] --
// block: (hw-tile of 112, mgroup of 96 out-ch, n); 384 thr = 6 waves, wave = one 16-row tile
__global__ __launch_bounds__(384) void k1_expand(const float* __restrict__ x,
                                                 const _Float16* __restrict__ w_exp_h,
                                                 const float* __restrict__ b_exp,
                                                 _Float16* __restrict__ e_s) {
  __shared__ _Float16 x_lds[112][104];   // [hw_local][ci], pad 96->104 (2-way max on b128 reads)
  const int tid = threadIdx.x;
  const int n   = blockIdx.z;
  const int co0 = blockIdx.y * 96;
  const int hw0 = blockIdx.x * 112;

  // stage x tile transposed, minus zero-point (values are exact small ints)
  for (int idx = tid; idx < CI * 28; idx += 384) {
    int c = idx / 28, seg = idx % 28;
    const float4 v = *(const float4*)&x[(n * CI + c) * HW + hw0 + seg * 4];
    int row = seg * 4;
    x_lds[row + 0][c] = (_Float16)(v.x - 128.0f);
    x_lds[row + 1][c] = (_Float16)(v.y - 128.0f);
    x_lds[row + 2][c] = (_Float16)(v.z - 128.0f);
    x_lds[row + 3][c] = (_Float16)(v.w - 128.0f);
  }
  __syncthreads();

  const int wv = tid >> 6, lane = tid & 63;
  const int l15 = lane & 15, q = lane >> 4;

  const _Float16* wrow = &w_exp_h[(co0 + wv * 16 + l15) * CI + q * 8];
  v8h a0 = *(const v8h*)(wrow);
  v8h a1 = *(const v8h*)(wrow + 32);
  v8h a2 = *(const v8h*)(wrow + 64);

  v4f acc[7];
#pragma unroll
  for (int t = 0; t < 7; ++t) acc[t] = (v4f){0.f, 0.f, 0.f, 0.f};

#pragma unroll
  for (int t = 0; t < 7; ++t) {
    const _Float16* bp = &x_lds[t * 16 + l15][q * 8];
    v8h b0 = *(const v8h*)(bp);
    v8h b1 = *(const v8h*)(bp + 32);
    v8h b2 = *(const v8h*)(bp + 64);
    acc[t] = __builtin_amdgcn_mfma_f32_16x16x32_f16(a0, b0, acc[t], 0, 0, 0);
    acc[t] = __builtin_amdgcn_mfma_f32_16x16x32_f16(a1, b1, acc[t], 0, 0, 0);
    acc[t] = __builtin_amdgcn_mfma_f32_16x16x32_f16(a2, b2, acc[t], 0, 0, 0);
  }

  float bia[4];
#pragma unroll
  for (int r = 0; r < 4; ++r) bia[r] = b_exp[co0 + wv * 16 + q * 4 + r];

#pragma unroll
  for (int t = 0; t < 7; ++t) {
#pragma unroll
    for (int r = 0; r < 4; ++r) {
      int co = co0 + wv * 16 + q * 4 + r;
      int hw = hw0 + t * 16 + l15;
      float deq = (acc[t][r] + bia[r]) * 5.0e-4f;            // S_IN * W_SCALE
      float cl  = fminf(fmaxf(deq + 3.0f, 0.0f), 6.0f);
      float hs  = deq * cl * (1.0f / 6.0f);
      float ev  = fminf(fmaxf(hs * 25.0f, -128.0f), 127.0f); // (e - 128)
      e_s[(n * CE + co) * HW + hw] = (_Float16)ev;
    }
  }
}

// ---------------- K2: depthwise 5x5 + hardswish + requant + pool sums ---------
// block: (c-group of 8, n); 256 thr. LDS: zero-padded [8][32][32] image tile.
__global__ __launch_bounds__(256) void k2_dw(const _Float16* __restrict__ e_s,
                                             const float* __restrict__ w_dw,
                                             const float* __restrict__ b_dw,
                                             _Float16* __restrict__ d_s,
                                             float* __restrict__ d_sums) {
  __shared__ _Float16 e_lds[8][32][32];
  __shared__ float w_lds[8][25];
  const int tid = threadIdx.x;
  const int n = blockIdx.y;
  const int c0 = blockIdx.x * 8;

  unsigned int* z = (unsigned int*)&e_lds[0][0][0];
  for (int idx = tid; idx < 8 * 32 * 32 / 2; idx += 256) z[idx] = 0u;
  __syncthreads();
  for (int idx = tid; idx < 8 * 392; idx += 256) {   // interior, 2 halfs per load
    int c = idx / 392, r2 = idx % 392;
    int y = r2 / 14, xp = (r2 % 14) * 2;
    unsigned int v = *(const unsigned int*)&e_s[(n * CE + c0 + c) * HW + y * 28 + xp];
    *(unsigned int*)&e_lds[c][y + 2][xp + 2] = v;
  }
  for (int idx = tid; idx < 8 * 25; idx += 256)
    w_lds[idx / 25][idx % 25] = w_dw[(c0 + idx / 25) * 25 + idx % 25];
  __syncthreads();

  const int c = tid >> 5, lane = tid & 31;
  float wv[25];
#pragma unroll
  for (int i = 0; i < 25; ++i) wv[i] = w_lds[c][i];
  const float bc = b_dw[c0 + c];

  float csum = 0.0f;
  for (int qd = lane; qd < 196; qd += 32) {   // 4 outputs along x per iter
    int y = qd / 7;
    int x0 = (qd % 7) * 4;
    float o0 = bc, o1 = bc, o2 = bc, o3 = bc;
#pragma unroll
    for (int dy = 0; dy < 5; ++dy) {
      const _Float16* row = &e_lds[c][y + dy][x0];
      v4h r0 = *(const v4h*)(row);
      v4h r1 = *(const v4h*)(row + 4);
      float f0 = (float)r0[0], f1 = (float)r0[1], f2 = (float)r0[2], f3 = (float)r0[3];
      float f4 = (float)r1[0], f5 = (float)r1[1], f6 = (float)r1[2], f7 = (float)r1[3];
      const float w0 = wv[dy * 5], w1 = wv[dy * 5 + 1], w2 = wv[dy * 5 + 2],
                  w3 = wv[dy * 5 + 3], w4 = wv[dy * 5 + 4];
      o0 += f0 * w0 + f1 * w1 + f2 * w2 + f3 * w3 + f4 * w4;
      o1 += f1 * w0 + f2 * w1 + f3 * w2 + f4 * w3 + f5 * w4;
      o2 += f2 * w0 + f3 * w1 + f4 * w2 + f5 * w3 + f6 * w4;
      o3 += f3 * w0 + f4 * w1 + f5 * w2 + f6 * w3 + f7 * w4;
    }
    v4h dv;
    float oo[4] = {o0, o1, o2, o3};
#pragma unroll
    for (int i = 0; i < 4; ++i) {
      float deq = oo[i] * 4.0e-4f;            // S1 * W_SCALE
      float cl  = fminf(fmaxf(deq + 3.0f, 0.0f), 6.0f);
      float hs  = deq * cl * (1.0f / 6.0f);
      float dvv = fminf(fmaxf(hs * 25.0f, -128.0f), 127.0f); // (d - 128)
      dv[i] = (_Float16)dvv;
      csum += dvv;
    }
    *(v4h*)&d_s[(n * CE + c0 + c) * HW + y * 28 + x0] = dv;
  }
#pragma unroll
  for (int m = 16; m >= 1; m >>= 1) csum += __shfl_xor(csum, m);
  if (lane == 0) d_sums[n * CE + c0 + c] = csum;
}

// ---------------- K3: SE (fc1 -> fc2 hardsigmoid) -> gate g2' in [0,1] --------
__global__ __launch_bounds__(256) void k3_se(const float* __restrict__ d_sums,
                                             const float* __restrict__ w_se1,
                                             const float* __restrict__ b_se1,
                                             const float* __restrict__ w_se2,
                                             const float* __restrict__ b_se2,
                                             float* __restrict__ g2p) {
  __shared__ float pooled[CE];
  __shared__ float g1s[SEC];
  const int tid = threadIdx.x;
  const int n = blockIdx.x;
  for (int i = tid; i < CE; i += 256) pooled[i] = d_sums[n * CE + i] * (1.0f / 784.0f);
  __syncthreads();
  const int wv = tid >> 6, lane = tid & 63;
  for (int o = wv; o < SEC; o += 4) {
    float p = 0.f;
    for (int cc = lane; cc < CE; cc += 64) p += w_se1[o * CE + cc] * pooled[cc];
#pragma unroll
    for (int m = 32; m >= 1; m >>= 1) p += __shfl_xor(p, m);
    if (lane == 0) {
      float deq = (p + b_se1[o]) * 4.0e-4f;   // S2 * W_SCALE
      g1s[o] = fminf(fmaxf(deq * 33.3333333f + 128.0f, 0.0f), 255.0f) - 128.0f;
    }
  }
  __syncthreads();
  for (int o = wv; o < CE; o += 4) {
    float p = 0.f;
    for (int i = lane; i < SEC; i += 64) p += w_se2[o * SEC + i] * g1s[i];
#pragma unroll
    for (int m = 32; m >= 1; m >>= 1) p += __shfl_xor(p, m);
    if (lane == 0) {
      float deq = (p + b_se2[o]) * 3.0e-4f;   // S_SE1 * W_SCALE
      g2p[n * CE + o] = fminf(fmaxf(deq + 3.0f, 0.0f), 6.0f) * (1.0f / 6.0f); // hardsigmoid
    }
  }
}

// ---------------- K4: gated project 1x1 + residual add -> out fp32 -----------
// block: (hw-tile of 112, n); 384 thr = 6 waves, wave = one 16-row tile of M=96
__global__ __launch_bounds__(384) void k4_proj(const _Float16* __restrict__ d_s,
                                               const float* __restrict__ g2p,
                                               const _Float16* __restrict__ w_proj_h,
                                               const float* __restrict__ b_proj,
                                               const float* __restrict__ x,
                                               float* __restrict__ out) {
  __shared__ _Float16 B_lds[112][40];   // [hw_local][k], pad 32->40 (16B aligned, 2-way)
  __shared__ float g2l[CE];
  const int tid = threadIdx.x;
  const int n = blockIdx.y;
  const int hw0 = blockIdx.x * 112;

  for (int i = tid; i < CE; i += 384) g2l[i] = g2p[n * CE + i];
  __syncthreads();

  const int wv = tid >> 6, lane = tid & 63;
  const int l15 = lane & 15, q = lane >> 4;

  v4f acc[7];
#pragma unroll
  for (int t = 0; t < 7; ++t) acc[t] = (v4f){0.f, 0.f, 0.f, 0.f};

  for (int ks = 0; ks < 18; ++ks) {
    // stage gated B tile: B[k][hw] = g2'[c] * d_s, transposed into [hw][k]
    for (int idx = tid; idx < 896; idx += 384) {
      int cg = idx / 28, seg = idx % 28;
      int cc = ks * 32 + cg;
      v4h dv = *(const v4h*)&d_s[(n * CE + cc) * HW + hw0 + seg * 4];
      float g = g2l[cc];
      int r0 = seg * 4;
      B_lds[r0 + 0][cg] = (_Float16)(g * (float)dv[0]);
      B_lds[r0 + 1][cg] = (_Float16)(g * (float)dv[1]);
      B_lds[r0 + 2][cg] = (_Float16)(g * (float)dv[2]);
      B_lds[r0 + 3][cg] = (_Float16)(g * (float)dv[3]);
    }
    __syncthreads();
    v8h a = *(const v8h*)&w_proj_h[(wv * 16 + l15) * CE + ks * 32 + q * 8];
#pragma unroll
    for (int t = 0; t < 7; ++t) {
      v8h b = *(const v8h*)&B_lds[t * 16 + l15][q * 8];
      acc[t] = __builtin_amdgcn_mfma_f32_16x16x32_f16(a, b, acc[t], 0, 0, 0);
    }
    __syncthreads();
  }

  float bia[4];
#pragma unroll
  for (int r = 0; r < 4; ++r) bia[r] = b_proj[wv * 16 + q * 4 + r];

#pragma unroll
  for (int t = 0; t < 7; ++t) {
#pragma unroll
    for (int r = 0; r < 4; ++r) {
      int co = wv * 16 + q * 4 + r;
      int hw = hw0 + t * 16 + l15;
      float p = fminf(fmaxf((acc[t][r] + bia[r]) * 4.0e-4f * 20.0f + 128.0f, 0.0f), 255.0f);
      float xv = x[(n * CO + co) * HW + hw];
      float o = (xv - 128.0f) * 0.8333333333f + (p - 128.0f) * 0.8333333333f + 128.0f;
      out[(n * CO + co) * HW + hw] = fminf(fmaxf(o, 0.0f), 255.0f);
    }
  }
}

extern "C" void kernel_launch(void* const* d_in, const int* in_sizes, int n_in,
                              void* d_out, int out_size, void* d_ws, size_t ws_size,
                              hipStream_t stream) {
  const float* x      = (const float*)d_in[0];
  const float* w_exp  = (const float*)d_in[1];
  const float* b_exp  = (const float*)d_in[2];
  const float* w_dw   = (const float*)d_in[3];
  const float* b_dw   = (const float*)d_in[4];
  const float* w_se1  = (const float*)d_in[5];
  const float* b_se1  = (const float*)d_in[6];
  const float* w_se2  = (const float*)d_in[7];
  const float* b_se2  = (const float*)d_in[8];
  const float* w_proj = (const float*)d_in[9];
  const float* b_proj = (const float*)d_in[10];
  float* out = (float*)d_out;

  char* ws = (char*)d_ws;
  const size_t SZ_W  = (size_t)CE * CI * 2;            // 110592 B
  const size_t SZ_ED = (size_t)NB * CE * HW * 2;       // 57802752 B
  const size_t SZ_S  = (size_t)NB * CE * 4;            // 147456 B
  _Float16* w_exp_h  = (_Float16*)(ws);
  _Float16* w_proj_h = (_Float16*)(ws + SZ_W);
  _Float16* e_s      = (_Float16*)(ws + 2 * SZ_W);
  _Float16* d_s      = (_Float16*)(ws + 2 * SZ_W + SZ_ED);
  float*    d_sums   = (float*)   (ws + 2 * SZ_W + 2 * SZ_ED);
  float*    g2p      = (float*)   (ws + 2 * SZ_W + 2 * SZ_ED + SZ_S);
  // total ws use: 2*110592 + 2*57802752 + 2*147456 = 116,121,600 B

  k0_cvt_w<<<(CE * CI + 255) / 256, 256, 0, stream>>>(w_exp, w_proj, w_exp_h, w_proj_h);
  k1_expand<<<dim3(7, 6, NB), 384, 0, stream>>>(x, w_exp_h, b_exp, e_s);
  k2_dw<<<dim3(72, NB), 256, 0, stream>>>(e_s, w_dw, b_dw, d_s, d_sums);
  k3_se<<<NB, 256, 0, stream>>>(d_sums, w_se1, b_se1, w_se2, b_se2, g2p);
  k4_proj<<<dim3(7, NB), 384, 0, stream>>>(d_s, g2p, w_proj_h, b_proj, x, out);
}

// Round 2
// 222.957 us; speedup vs baseline: 1.8940x; 1.8940x over previous
//
#include <hip/hip_runtime.h>

typedef _Float16 v8h __attribute__((ext_vector_type(8)));
typedef _Float16 v4h __attribute__((ext_vector_type(4)));
typedef float v4f __attribute__((ext_vector_type(4)));

#define NB 64
#define CI 96
#define CE 576
#define CO 96
#define HW 784
#define SEC 144

// ---------------- K0: convert GEMM weights to fp16 (integers +-127, exact) ----
__global__ __launch_bounds__(256) void k0_cvt_w(const float* __restrict__ w_exp,
                                                const float* __restrict__ w_proj,
                                                _Float16* __restrict__ w_exp_h,
                                                _Float16* __restrict__ w_proj_h) {
  int i = blockIdx.x * 256 + threadIdx.x;
  if (i < CE * CI) {                 // 55296 == CE*CI == CO*CE
    w_exp_h[i]  = (_Float16)w_exp[i];
    w_proj_h[i] = (_Float16)w_proj[i];
  }
}

// ---------------- K1: expand 1x1 + hardswish + requant -> e_s fp16 [n][c][hw] --
// block: (hw-tile of 112, mgroup of 96 out-ch, n); 384 thr = 6 waves, wave = one 16-row tile
__global__ __launch_bounds__(384) void k1_expand(const float* __restrict__ x,
                                                 const _Float16* __restrict__ w_exp_h,
                                                 const float* __restrict__ b_exp,
                                                 _Float16* __restrict__ e_s) {
  __shared__ _Float16 x_lds[112][104];   // [hw_local][ci], pad 96->104 (2-way max on b128 reads)
  const int tid = threadIdx.x;
  const int n   = blockIdx.z;
  const int co0 = blockIdx.y * 96;
  const int hw0 = blockIdx.x * 112;

  // stage x tile transposed, minus zero-point (values are exact small ints)
  for (int idx = tid; idx < CI * 28; idx += 384) {
    int c = idx / 28, seg = idx % 28;
    const float4 v = *(const float4*)&x[(n * CI + c) * HW + hw0 + seg * 4];
    int row = seg * 4;
    x_lds[row + 0][c] = (_Float16)(v.x - 128.0f);
    x_lds[row + 1][c] = (_Float16)(v.y - 128.0f);
    x_lds[row + 2][c] = (_Float16)(v.z - 128.0f);
    x_lds[row + 3][c] = (_Float16)(v.w - 128.0f);
  }
  __syncthreads();

  const int wv = tid >> 6, lane = tid & 63;
  const int l15 = lane & 15, q = lane >> 4;

  const _Float16* wrow = &w_exp_h[(co0 + wv * 16 + l15) * CI + q * 8];
  v8h a0 = *(const v8h*)(wrow);
  v8h a1 = *(const v8h*)(wrow + 32);
  v8h a2 = *(const v8h*)(wrow + 64);

  v4f acc[7];
#pragma unroll
  for (int t = 0; t < 7; ++t) acc[t] = (v4f){0.f, 0.f, 0.f, 0.f};

#pragma unroll
  for (int t = 0; t < 7; ++t) {
    const _Float16* bp = &x_lds[t * 16 + l15][q * 8];
    v8h b0 = *(const v8h*)(bp);
    v8h b1 = *(const v8h*)(bp + 32);
    v8h b2 = *(const v8h*)(bp + 64);
    acc[t] = __builtin_amdgcn_mfma_f32_16x16x32_f16(a0, b0, acc[t], 0, 0, 0);
    acc[t] = __builtin_amdgcn_mfma_f32_16x16x32_f16(a1, b1, acc[t], 0, 0, 0);
    acc[t] = __builtin_amdgcn_mfma_f32_16x16x32_f16(a2, b2, acc[t], 0, 0, 0);
  }

  float bia[4];
#pragma unroll
  for (int r = 0; r < 4; ++r) bia[r] = b_exp[co0 + wv * 16 + q * 4 + r];

#pragma unroll
  for (int t = 0; t < 7; ++t) {
#pragma unroll
    for (int r = 0; r < 4; ++r) {
      int co = co0 + wv * 16 + q * 4 + r;
      int hw = hw0 + t * 16 + l15;
      float deq = (acc[t][r] + bia[r]) * 5.0e-4f;            // S_IN * W_SCALE
      float cl  = fminf(fmaxf(deq + 3.0f, 0.0f), 6.0f);
      float hs  = deq * cl * (1.0f / 6.0f);
      float ev  = fminf(fmaxf(hs * 25.0f, -128.0f), 127.0f); // (e - 128)
      e_s[(n * CE + co) * HW + hw] = (_Float16)ev;
    }
  }
}

// ---------------- K2: depthwise 5x5 + hardswish + requant + pool sums ---------
// block: (c-group of 8, n); 256 thr. LDS: zero-padded [8][32][32] image tile.
__global__ __launch_bounds__(256) void k2_dw(const _Float16* __restrict__ e_s,
                                             const float* __restrict__ w_dw,
                                             const float* __restrict__ b_dw,
                                             _Float16* __restrict__ d_s,
                                             float* __restrict__ d_sums) {
  __shared__ _Float16 e_lds[8][32][32];
  __shared__ float w_lds[8][25];
  const int tid = threadIdx.x;
  const int n = blockIdx.y;
  const int c0 = blockIdx.x * 8;

  unsigned int* z = (unsigned int*)&e_lds[0][0][0];
  for (int idx = tid; idx < 8 * 32 * 32 / 2; idx += 256) z[idx] = 0u;
  __syncthreads();
  for (int idx = tid; idx < 8 * 392; idx += 256) {   // interior, 2 halfs per load
    int c = idx / 392, r2 = idx % 392;
    int y = r2 / 14, xp = (r2 % 14) * 2;
    unsigned int v = *(const unsigned int*)&e_s[(n * CE + c0 + c) * HW + y * 28 + xp];
    *(unsigned int*)&e_lds[c][y + 2][xp + 2] = v;
  }
  for (int idx = tid; idx < 8 * 25; idx += 256)
    w_lds[idx / 25][idx % 25] = w_dw[(c0 + idx / 25) * 25 + idx % 25];
  __syncthreads();

  const int c = tid >> 5, lane = tid & 31;
  float wv[25];
#pragma unroll
  for (int i = 0; i < 25; ++i) wv[i] = w_lds[c][i];
  const float bc = b_dw[c0 + c];

  float csum = 0.0f;
  for (int qd = lane; qd < 196; qd += 32) {   // 4 outputs along x per iter
    int y = qd / 7;
    int x0 = (qd % 7) * 4;
    float o0 = bc, o1 = bc, o2 = bc, o3 = bc;
#pragma unroll
    for (int dy = 0; dy < 5; ++dy) {
      const _Float16* row = &e_lds[c][y + dy][x0];
      v4h r0 = *(const v4h*)(row);
      v4h r1 = *(const v4h*)(row + 4);
      float f0 = (float)r0[0], f1 = (float)r0[1], f2 = (float)r0[2], f3 = (float)r0[3];
      float f4 = (float)r1[0], f5 = (float)r1[1], f6 = (float)r1[2], f7 = (float)r1[3];
      const float w0 = wv[dy * 5], w1 = wv[dy * 5 + 1], w2 = wv[dy * 5 + 2],
                  w3 = wv[dy * 5 + 3], w4 = wv[dy * 5 + 4];
      o0 += f0 * w0 + f1 * w1 + f2 * w2 + f3 * w3 + f4 * w4;
      o1 += f1 * w0 + f2 * w1 + f3 * w2 + f4 * w3 + f5 * w4;
      o2 += f2 * w0 + f3 * w1 + f4 * w2 + f5 * w3 + f6 * w4;
      o3 += f3 * w0 + f4 * w1 + f5 * w2 + f6 * w3 + f7 * w4;
    }
    v4h dv;
    float oo[4] = {o0, o1, o2, o3};
#pragma unroll
    for (int i = 0; i < 4; ++i) {
      float deq = oo[i] * 4.0e-4f;            // S1 * W_SCALE
      float cl  = fminf(fmaxf(deq + 3.0f, 0.0f), 6.0f);
      float hs  = deq * cl * (1.0f / 6.0f);
      float dvv = fminf(fmaxf(hs * 25.0f, -128.0f), 127.0f); // (d - 128)
      dv[i] = (_Float16)dvv;
      csum += dvv;
    }
    *(v4h*)&d_s[(n * CE + c0 + c) * HW + y * 28 + x0] = dv;
  }
#pragma unroll
  for (int m = 16; m >= 1; m >>= 1) csum += __shfl_xor(csum, m);
  if (lane == 0) d_sums[n * CE + c0 + c] = csum;
}

// ---------------- K3a: SE fc1 — one wave per (n, o) dot of length 576 ---------
__global__ __launch_bounds__(256) void k3a_fc1(const float* __restrict__ d_sums,
                                               const float* __restrict__ w_se1,
                                               const float* __restrict__ b_se1,
                                               float* __restrict__ g1) {
  const int tid = threadIdx.x;
  const int wv = tid >> 6, lane = tid & 63;
  const int n = blockIdx.y;
  const int o = blockIdx.x * 4 + wv;       // 144 outputs
  const float* wrow = &w_se1[o * CE];
  const float* srow = &d_sums[n * CE];
  float p = 0.f;
#pragma unroll
  for (int s = 0; s < 9; ++s) {
    int cc = lane + s * 64;
    p += wrow[cc] * srow[cc];
  }
#pragma unroll
  for (int m = 32; m >= 1; m >>= 1) p += __shfl_xor(p, m);
  if (lane == 0) {
    // pooled-z = d_sums/784 (d_s already stores d-128)
    float deq = (p * (1.0f / 784.0f) + b_se1[o]) * 4.0e-4f;  // S2 * W_SCALE
    g1[n * SEC + o] = fminf(fmaxf(deq * 33.3333333f + 128.0f, 0.0f), 255.0f) - 128.0f;
  }
}

// ---------------- K3b: SE fc2 + hardsigmoid — one wave per (n, o), K=144 ------
__global__ __launch_bounds__(256) void k3b_fc2(const float* __restrict__ g1,
                                               const float* __restrict__ w_se2,
                                               const float* __restrict__ b_se2,
                                               float* __restrict__ g2p) {
  const int tid = threadIdx.x;
  const int wv = tid >> 6, lane = tid & 63;
  const int n = blockIdx.y;
  const int o = blockIdx.x * 4 + wv;       // 576 outputs
  const float* wrow = &w_se2[o * SEC];
  const float* grow = &g1[n * SEC];
  float p = wrow[lane] * grow[lane] + wrow[lane + 64] * grow[lane + 64];
  if (lane < 16) p += wrow[lane + 128] * grow[lane + 128];
#pragma unroll
  for (int m = 32; m >= 1; m >>= 1) p += __shfl_xor(p, m);
  if (lane == 0) {
    float deq = (p + b_se2[o]) * 3.0e-4f;  // S_SE1 * W_SCALE
    g2p[n * CE + o] = fminf(fmaxf(deq + 3.0f, 0.0f), 6.0f) * (1.0f / 6.0f); // hardsigmoid
  }
}

// ---------------- K4: gated project 1x1 + residual add -> out fp32 -----------
// block: (hw-tile of 112, n); 384 thr = 6 waves, wave = one 16-row tile of M=96
__global__ __launch_bounds__(384) void k4_proj(const _Float16* __restrict__ d_s,
                                               const float* __restrict__ g2p,
                                               const _Float16* __restrict__ w_proj_h,
                                               const float* __restrict__ b_proj,
                                               const float* __restrict__ x,
                                               float* __restrict__ out) {
  __shared__ _Float16 B_lds[112][40];   // [hw_local][k], pad 32->40 (16B aligned, 2-way)
  __shared__ float g2l[CE];
  const int tid = threadIdx.x;
  const int n = blockIdx.y;
  const int hw0 = blockIdx.x * 112;

  for (int i = tid; i < CE; i += 384) g2l[i] = g2p[n * CE + i];
  __syncthreads();

  const int wv = tid >> 6, lane = tid & 63;
  const int l15 = lane & 15, q = lane >> 4;

  v4f acc[7];
#pragma unroll
  for (int t = 0; t < 7; ++t) acc[t] = (v4f){0.f, 0.f, 0.f, 0.f};

  for (int ks = 0; ks < 18; ++ks) {
    // stage gated B tile: B[k][hw] = g2'[c] * d_s, transposed into [hw][k]
    for (int idx = tid; idx < 896; idx += 384) {
      int cg = idx / 28, seg = idx % 28;
      int cc = ks * 32 + cg;
      v4h dv = *(const v4h*)&d_s[(n * CE + cc) * HW + hw0 + seg * 4];
      float g = g2l[cc];
      int r0 = seg * 4;
      B_lds[r0 + 0][cg] = (_Float16)(g * (float)dv[0]);
      B_lds[r0 + 1][cg] = (_Float16)(g * (float)dv[1]);
      B_lds[r0 + 2][cg] = (_Float16)(g * (float)dv[2]);
      B_lds[r0 + 3][cg] = (_Float16)(g * (float)dv[3]);
    }
    __syncthreads();
    v8h a = *(const v8h*)&w_proj_h[(wv * 16 + l15) * CE + ks * 32 + q * 8];
#pragma unroll
    for (int t = 0; t < 7; ++t) {
      v8h b = *(const v8h*)&B_lds[t * 16 + l15][q * 8];
      acc[t] = __builtin_amdgcn_mfma_f32_16x16x32_f16(a, b, acc[t], 0, 0, 0);
    }
    __syncthreads();
  }

  float bia[4];
#pragma unroll
  for (int r = 0; r < 4; ++r) bia[r] = b_proj[wv * 16 + q * 4 + r];

#pragma unroll
  for (int t = 0; t < 7; ++t) {
#pragma unroll
    for (int r = 0; r < 4; ++r) {
      int co = wv * 16 + q * 4 + r;
      int hw = hw0 + t * 16 + l15;
      float p = fminf(fmaxf((acc[t][r] + bia[r]) * 4.0e-4f * 20.0f + 128.0f, 0.0f), 255.0f);
      float xv = x[(n * CO + co) * HW + hw];
      float o = (xv - 128.0f) * 0.8333333333f + (p - 128.0f) * 0.8333333333f + 128.0f;
      out[(n * CO + co) * HW + hw] = fminf(fmaxf(o, 0.0f), 255.0f);
    }
  }
}

extern "C" void kernel_launch(void* const* d_in, const int* in_sizes, int n_in,
                              void* d_out, int out_size, void* d_ws, size_t ws_size,
                              hipStream_t stream) {
  const float* x      = (const float*)d_in[0];
  const float* w_exp  = (const float*)d_in[1];
  const float* b_exp  = (const float*)d_in[2];
  const float* w_dw   = (const float*)d_in[3];
  const float* b_dw   = (const float*)d_in[4];
  const float* w_se1  = (const float*)d_in[5];
  const float* b_se1  = (const float*)d_in[6];
  const float* w_se2  = (const float*)d_in[7];
  const float* b_se2  = (const float*)d_in[8];
  const float* w_proj = (const float*)d_in[9];
  const float* b_proj = (const float*)d_in[10];
  float* out = (float*)d_out;

  char* ws = (char*)d_ws;
  const size_t SZ_W  = (size_t)CE * CI * 2;            // 110592 B
  const size_t SZ_ED = (size_t)NB * CE * HW * 2;       // 57802752 B
  const size_t SZ_S  = (size_t)NB * CE * 4;            // 147456 B
  _Float16* w_exp_h  = (_Float16*)(ws);
  _Float16* w_proj_h = (_Float16*)(ws + SZ_W);
  _Float16* e_s      = (_Float16*)(ws + 2 * SZ_W);
  _Float16* d_s      = (_Float16*)(ws + 2 * SZ_W + SZ_ED);
  float*    d_sums   = (float*)   (ws + 2 * SZ_W + 2 * SZ_ED);
  float*    g2p      = (float*)   (ws + 2 * SZ_W + 2 * SZ_ED + SZ_S);
  float*    g1       = (float*)   (ws + 2 * SZ_W + 2 * SZ_ED + 2 * SZ_S);
  // total ws use: ~116.3 MB

  k0_cvt_w<<<(CE * CI + 255) / 256, 256, 0, stream>>>(w_exp, w_proj, w_exp_h, w_proj_h);
  k1_expand<<<dim3(7, 6, NB), 384, 0, stream>>>(x, w_exp_h, b_exp, e_s);
  k2_dw<<<dim3(72, NB), 256, 0, stream>>>(e_s, w_dw, b_dw, d_s, d_sums);
  k3a_fc1<<<dim3(36, NB), 256, 0, stream>>>(d_sums, w_se1, b_se1, g1);
  k3b_fc2<<<dim3(144, NB), 256, 0, stream>>>(g1, w_se2, b_se2, g2p);
  k4_proj<<<dim3(7, NB), 384, 0, stream>>>(d_s, g2p, w_proj_h, b_proj, x, out);
}

// Round 3
// 207.105 us; speedup vs baseline: 2.0390x; 1.0765x over previous
//
#include <hip/hip_runtime.h>

typedef _Float16 v8h __attribute__((ext_vector_type(8)));
typedef _Float16 v4h __attribute__((ext_vector_type(4)));
typedef _Float16 v2h __attribute__((ext_vector_type(2)));
typedef float v4f __attribute__((ext_vector_type(4)));

#define NB 64
#define CI 96
#define CE 576
#define CO 96
#define HW 784
#define SEC 144

#if defined(__has_builtin)
#if __has_builtin(__builtin_amdgcn_fdot2)
#define HAVE_FDOT2 1
#endif
#endif

__device__ __forceinline__ float fdot2(v2h a, v2h b, float c) {
#ifdef HAVE_FDOT2
  return __builtin_amdgcn_fdot2(a, b, c, false);
#else
  return (float)a[0] * (float)b[0] + ((float)a[1] * (float)b[1] + c);
#endif
}

// ---------------- K0: convert GEMM weights to fp16 (integers +-127, exact) ----
__global__ __launch_bounds__(256) void k0_cvt_w(const float* __restrict__ w_exp,
                                                const float* __restrict__ w_proj,
                                                _Float16* __restrict__ w_exp_h,
                                                _Float16* __restrict__ w_proj_h) {
  int i = blockIdx.x * 256 + threadIdx.x;
  if (i < CE * CI) {                 // 55296 == CE*CI == CO*CE
    w_exp_h[i]  = (_Float16)w_exp[i];
    w_proj_h[i] = (_Float16)w_proj[i];
  }
}

// ---------------- K1: expand 1x1 + hardswish + requant -> e_s fp16 [n][c][hw] --
// block: (hw-tile of 112, mgroup of 96 out-ch, n); 384 thr = 6 waves, wave = one 16-row tile
__global__ __launch_bounds__(384) void k1_expand(const float* __restrict__ x,
                                                 const _Float16* __restrict__ w_exp_h,
                                                 const float* __restrict__ b_exp,
                                                 _Float16* __restrict__ e_s) {
  __shared__ _Float16 x_lds[112][104];   // [hw_local][ci], pad 96->104 (2-way max on b128 reads)
  const int tid = threadIdx.x;
  const int n   = blockIdx.z;
  const int co0 = blockIdx.y * 96;
  const int hw0 = blockIdx.x * 112;

  // stage x tile transposed, minus zero-point (values are exact small ints)
  for (int idx = tid; idx < CI * 28; idx += 384) {
    int c = idx / 28, seg = idx % 28;
    const float4 v = *(const float4*)&x[(n * CI + c) * HW + hw0 + seg * 4];
    int row = seg * 4;
    x_lds[row + 0][c] = (_Float16)(v.x - 128.0f);
    x_lds[row + 1][c] = (_Float16)(v.y - 128.0f);
    x_lds[row + 2][c] = (_Float16)(v.z - 128.0f);
    x_lds[row + 3][c] = (_Float16)(v.w - 128.0f);
  }
  __syncthreads();

  const int wv = tid >> 6, lane = tid & 63;
  const int l15 = lane & 15, q = lane >> 4;

  const _Float16* wrow = &w_exp_h[(co0 + wv * 16 + l15) * CI + q * 8];
  v8h a0 = *(const v8h*)(wrow);
  v8h a1 = *(const v8h*)(wrow + 32);
  v8h a2 = *(const v8h*)(wrow + 64);

  v4f acc[7];
#pragma unroll
  for (int t = 0; t < 7; ++t) acc[t] = (v4f){0.f, 0.f, 0.f, 0.f};

#pragma unroll
  for (int t = 0; t < 7; ++t) {
    const _Float16* bp = &x_lds[t * 16 + l15][q * 8];
    v8h b0 = *(const v8h*)(bp);
    v8h b1 = *(const v8h*)(bp + 32);
    v8h b2 = *(const v8h*)(bp + 64);
    acc[t] = __builtin_amdgcn_mfma_f32_16x16x32_f16(a0, b0, acc[t], 0, 0, 0);
    acc[t] = __builtin_amdgcn_mfma_f32_16x16x32_f16(a1, b1, acc[t], 0, 0, 0);
    acc[t] = __builtin_amdgcn_mfma_f32_16x16x32_f16(a2, b2, acc[t], 0, 0, 0);
  }

  float bia[4];
#pragma unroll
  for (int r = 0; r < 4; ++r) bia[r] = b_exp[co0 + wv * 16 + q * 4 + r];

#pragma unroll
  for (int t = 0; t < 7; ++t) {
#pragma unroll
    for (int r = 0; r < 4; ++r) {
      int co = co0 + wv * 16 + q * 4 + r;
      int hw = hw0 + t * 16 + l15;
      float deq = (acc[t][r] + bia[r]) * 5.0e-4f;            // S_IN * W_SCALE
      float cl  = fminf(fmaxf(deq + 3.0f, 0.0f), 6.0f);
      float hs  = deq * cl * (1.0f / 6.0f);
      float ev  = fminf(fmaxf(hs * 25.0f, -128.0f), 127.0f); // (e - 128)
      e_s[(n * CE + co) * HW + hw] = (_Float16)ev;
    }
  }
}

// ---------------- K2: depthwise 5x5 + hardswish + requant + pool sums ---------
// block: (c-group of 8, n); 256 thr. LDS: [8][32 rows][4 pad|28|4 pad] halfs.
// Each half-wave handles one channel; lane = output row y (lanes 28..31 idle in compute).
// Row conv via v_dot2_f32_f16 on v2h window pairs; x-slide reuses 2 of 4 pairs.
__global__ __launch_bounds__(256, 4) void k2_dw(const _Float16* __restrict__ e_s,
                                                const float* __restrict__ w_dw,
                                                const float* __restrict__ b_dw,
                                                _Float16* __restrict__ d_s,
                                                float* __restrict__ d_sums) {
  __shared__ _Float16 e_lds[8][32][36];   // row stride 72B = 18 banks (gcd 2 -> free)
  __shared__ _Float16 w_pairs[8][5][8];   // [c][dy][w0,w1,w2,w3, w1,w2,w3,w4]
  const int tid = threadIdx.x;
  const int n = blockIdx.y;
  const int c0 = blockIdx.x * 8;

  // zero the halo (whole buffer, cheap: 9 u64 stores/thread)
  {
    unsigned long long* z = (unsigned long long*)&e_lds[0][0][0];
    for (int idx = tid; idx < 8 * 32 * 36 * 2 / 8; idx += 256) z[idx] = 0ull;
  }
  // stage duplicated weight pairs (f16, exact for int weights)
  for (int idx = tid; idx < 320; idx += 256) {
    int c = idx / 40, r = idx % 40, dy = r / 8, k = r % 8;
    int tap = (k < 4) ? k : (k - 3);
    w_pairs[c][dy][k] = (_Float16)w_dw[(c0 + c) * 25 + dy * 5 + tap];
  }
  __syncthreads();
  // stage interior rows: 8 ch * 28 rows * 7 aligned b64 chunks
  for (int idx = tid; idx < 1568; idx += 256) {
    int c = idx / 196, r = idx % 196, y = r / 7, j = r % 7;
    v4h v = *(const v4h*)&e_s[(n * CE + c0 + c) * HW + y * 28 + j * 4];
    *(v4h*)&e_lds[c][2 + y][4 + j * 4] = v;
  }
  __syncthreads();

  const int c = tid >> 5, l = tid & 31;
  // hoist weights into registers
  v2h W01[5], W23[5], W12[5], W34[5];
  float W0s[5], W4s[5];
#pragma unroll
  for (int dy = 0; dy < 5; ++dy) {
    W01[dy] = *(const v2h*)&w_pairs[c][dy][0];
    W23[dy] = *(const v2h*)&w_pairs[c][dy][2];
    W12[dy] = *(const v2h*)&w_pairs[c][dy][4];
    W34[dy] = *(const v2h*)&w_pairs[c][dy][6];
    W0s[dy] = (float)W01[dy][0];
    W4s[dy] = (float)W34[dy][1];
  }
  const float bc = b_dw[c0 + c];

  float csum = 0.0f;
  if (l < 28) {
    const int y = l;   // output row; input rows y-2..y+2 -> LDS rows y..y+4
    // window pairs per dy: P0=(f0,f1) P1=(f2,f3) P2=(f4,f5) P3=(f6,f7),
    // f_k = pixel (x0-2+k), LDS half offset = pixel + 4
    v2h P0[5], P1[5], P2[5], P3[5];
#pragma unroll
    for (int dy = 0; dy < 5; ++dy) {
      const _Float16* row = &e_lds[c][y + dy][0];
      P0[dy] = *(const v2h*)(row + 2);
      P1[dy] = *(const v2h*)(row + 4);
      P2[dy] = *(const v2h*)(row + 6);
      P3[dy] = *(const v2h*)(row + 8);
    }
#pragma unroll
    for (int x0 = 0; x0 < 28; x0 += 4) {
      float o0 = bc, o1 = bc, o2 = bc, o3 = bc;
#pragma unroll
      for (int dy = 0; dy < 5; ++dy) {
        o0 = fdot2(P0[dy], W01[dy], o0);
        o0 = fdot2(P1[dy], W23[dy], o0);
        o0 += (float)P2[dy][0] * W4s[dy];
        o1 += (float)P0[dy][1] * W0s[dy];
        o1 = fdot2(P1[dy], W12[dy], o1);
        o1 = fdot2(P2[dy], W34[dy], o1);
        o2 = fdot2(P1[dy], W01[dy], o2);
        o2 = fdot2(P2[dy], W23[dy], o2);
        o2 += (float)P3[dy][0] * W4s[dy];
        o3 += (float)P1[dy][1] * W0s[dy];
        o3 = fdot2(P2[dy], W12[dy], o3);
        o3 = fdot2(P3[dy], W34[dy], o3);
      }
      v4h dv;
      float oo[4] = {o0, o1, o2, o3};
#pragma unroll
      for (int i = 0; i < 4; ++i) {
        float deq = oo[i] * 4.0e-4f;            // S1 * W_SCALE
        float cl  = fminf(fmaxf(deq + 3.0f, 0.0f), 6.0f);
        float hs  = deq * cl * (1.0f / 6.0f);
        float dvv = fminf(fmaxf(hs * 25.0f, -128.0f), 127.0f); // (d - 128)
        dv[i] = (_Float16)dvv;
        csum += dvv;
      }
      *(v4h*)&d_s[(n * CE + c0 + c) * HW + y * 28 + x0] = dv;
      if (x0 < 24) {
#pragma unroll
        for (int dy = 0; dy < 5; ++dy) {
          const _Float16* row = &e_lds[c][y + dy][0];
          P0[dy] = P2[dy];
          P1[dy] = P3[dy];
          P2[dy] = *(const v2h*)(row + x0 + 10);
          P3[dy] = *(const v2h*)(row + x0 + 12);
        }
      }
    }
  }
#pragma unroll
  for (int m = 16; m >= 1; m >>= 1) csum += __shfl_xor(csum, m);
  if (l == 0) d_sums[n * CE + c0 + c] = csum;
}

// ---------------- K3a: SE fc1 — one wave per (n, o) dot of length 576 ---------
__global__ __launch_bounds__(256) void k3a_fc1(const float* __restrict__ d_sums,
                                               const float* __restrict__ w_se1,
                                               const float* __restrict__ b_se1,
                                               float* __restrict__ g1) {
  const int tid = threadIdx.x;
  const int wv = tid >> 6, lane = tid & 63;
  const int n = blockIdx.y;
  const int o = blockIdx.x * 4 + wv;       // 144 outputs
  const float* wrow = &w_se1[o * CE];
  const float* srow = &d_sums[n * CE];
  float p = 0.f;
#pragma unroll
  for (int s = 0; s < 9; ++s) {
    int cc = lane + s * 64;
    p += wrow[cc] * srow[cc];
  }
#pragma unroll
  for (int m = 32; m >= 1; m >>= 1) p += __shfl_xor(p, m);
  if (lane == 0) {
    // pooled-z = d_sums/784 (d_s already stores d-128)
    float deq = (p * (1.0f / 784.0f) + b_se1[o]) * 4.0e-4f;  // S2 * W_SCALE
    g1[n * SEC + o] = fminf(fmaxf(deq * 33.3333333f + 128.0f, 0.0f), 255.0f) - 128.0f;
  }
}

// ---------------- K3b: SE fc2 + hardsigmoid — one wave per (n, o), K=144 ------
__global__ __launch_bounds__(256) void k3b_fc2(const float* __restrict__ g1,
                                               const float* __restrict__ w_se2,
                                               const float* __restrict__ b_se2,
                                               float* __restrict__ g2p) {
  const int tid = threadIdx.x;
  const int wv = tid >> 6, lane = tid & 63;
  const int n = blockIdx.y;
  const int o = blockIdx.x * 4 + wv;       // 576 outputs
  const float* wrow = &w_se2[o * SEC];
  const float* grow = &g1[n * SEC];
  float p = wrow[lane] * grow[lane] + wrow[lane + 64] * grow[lane + 64];
  if (lane < 16) p += wrow[lane + 128] * grow[lane + 128];
#pragma unroll
  for (int m = 32; m >= 1; m >>= 1) p += __shfl_xor(p, m);
  if (lane == 0) {
    float deq = (p + b_se2[o]) * 3.0e-4f;  // S_SE1 * W_SCALE
    g2p[n * CE + o] = fminf(fmaxf(deq + 3.0f, 0.0f), 6.0f) * (1.0f / 6.0f); // hardsigmoid
  }
}

// ---------------- K4: gated project 1x1 + residual add -> out fp32 -----------
// block: (hw-tile of 112, n); 384 thr = 6 waves, wave = one 16-row tile of M=96
__global__ __launch_bounds__(384) void k4_proj(const _Float16* __restrict__ d_s,
                                               const float* __restrict__ g2p,
                                               const _Float16* __restrict__ w_proj_h,
                                               const float* __restrict__ b_proj,
                                               const float* __restrict__ x,
                                               float* __restrict__ out) {
  __shared__ _Float16 B_lds[112][40];   // [hw_local][k], pad 32->40 (16B aligned, 2-way)
  __shared__ float g2l[CE];
  const int tid = threadIdx.x;
  const int n = blockIdx.y;
  const int hw0 = blockIdx.x * 112;

  for (int i = tid; i < CE; i += 384) g2l[i] = g2p[n * CE + i];
  __syncthreads();

  const int wv = tid >> 6, lane = tid & 63;
  const int l15 = lane & 15, q = lane >> 4;

  v4f acc[7];
#pragma unroll
  for (int t = 0; t < 7; ++t) acc[t] = (v4f){0.f, 0.f, 0.f, 0.f};

  for (int ks = 0; ks < 18; ++ks) {
    // stage gated B tile: B[k][hw] = g2'[c] * d_s, transposed into [hw][k]
    for (int idx = tid; idx < 896; idx += 384) {
      int cg = idx / 28, seg = idx % 28;
      int cc = ks * 32 + cg;
      v4h dv = *(const v4h*)&d_s[(n * CE + cc) * HW + hw0 + seg * 4];
      float g = g2l[cc];
      int r0 = seg * 4;
      B_lds[r0 + 0][cg] = (_Float16)(g * (float)dv[0]);
      B_lds[r0 + 1][cg] = (_Float16)(g * (float)dv[1]);
      B_lds[r0 + 2][cg] = (_Float16)(g * (float)dv[2]);
      B_lds[r0 + 3][cg] = (_Float16)(g * (float)dv[3]);
    }
    __syncthreads();
    v8h a = *(const v8h*)&w_proj_h[(wv * 16 + l15) * CE + ks * 32 + q * 8];
#pragma unroll
    for (int t = 0; t < 7; ++t) {
      v8h b = *(const v8h*)&B_lds[t * 16 + l15][q * 8];
      acc[t] = __builtin_amdgcn_mfma_f32_16x16x32_f16(a, b, acc[t], 0, 0, 0);
    }
    __syncthreads();
  }

  float bia[4];
#pragma unroll
  for (int r = 0; r < 4; ++r) bia[r] = b_proj[wv * 16 + q * 4 + r];

#pragma unroll
  for (int t = 0; t < 7; ++t) {
#pragma unroll
    for (int r = 0; r < 4; ++r) {
      int co = wv * 16 + q * 4 + r;
      int hw = hw0 + t * 16 + l15;
      float p = fminf(fmaxf((acc[t][r] + bia[r]) * 4.0e-4f * 20.0f + 128.0f, 0.0f), 255.0f);
      float xv = x[(n * CO + co) * HW + hw];
      float o = (xv - 128.0f) * 0.8333333333f + (p - 128.0f) * 0.8333333333f + 128.0f;
      out[(n * CO + co) * HW + hw] = fminf(fmaxf(o, 0.0f), 255.0f);
    }
  }
}

extern "C" void kernel_launch(void* const* d_in, const int* in_sizes, int n_in,
                              void* d_out, int out_size, void* d_ws, size_t ws_size,
                              hipStream_t stream) {
  const float* x      = (const float*)d_in[0];
  const float* w_exp  = (const float*)d_in[1];
  const float* b_exp  = (const float*)d_in[2];
  const float* w_dw   = (const float*)d_in[3];
  const float* b_dw   = (const float*)d_in[4];
  const float* w_se1  = (const float*)d_in[5];
  const float* b_se1  = (const float*)d_in[6];
  const float* w_se2  = (const float*)d_in[7];
  const float* b_se2  = (const float*)d_in[8];
  const float* w_proj = (const float*)d_in[9];
  const float* b_proj = (const float*)d_in[10];
  float* out = (float*)d_out;

  char* ws = (char*)d_ws;
  const size_t SZ_W  = (size_t)CE * CI * 2;            // 110592 B
  const size_t SZ_ED = (size_t)NB * CE * HW * 2;       // 57802752 B
  const size_t SZ_S  = (size_t)NB * CE * 4;            // 147456 B
  _Float16* w_exp_h  = (_Float16*)(ws);
  _Float16* w_proj_h = (_Float16*)(ws + SZ_W);
  _Float16* e_s      = (_Float16*)(ws + 2 * SZ_W);
  _Float16* d_s      = (_Float16*)(ws + 2 * SZ_W + SZ_ED);
  float*    d_sums   = (float*)   (ws + 2 * SZ_W + 2 * SZ_ED);
  float*    g2p      = (float*)   (ws + 2 * SZ_W + 2 * SZ_ED + SZ_S);
  float*    g1       = (float*)   (ws + 2 * SZ_W + 2 * SZ_ED + 2 * SZ_S);
  // total ws use: ~116.3 MB

  k0_cvt_w<<<(CE * CI + 255) / 256, 256, 0, stream>>>(w_exp, w_proj, w_exp_h, w_proj_h);
  k1_expand<<<dim3(7, 6, NB), 384, 0, stream>>>(x, w_exp_h, b_exp, e_s);
  k2_dw<<<dim3(72, NB), 256, 0, stream>>>(e_s, w_dw, b_dw, d_s, d_sums);
  k3a_fc1<<<dim3(36, NB), 256, 0, stream>>>(d_sums, w_se1, b_se1, g1);
  k3b_fc2<<<dim3(144, NB), 256, 0, stream>>>(g1, w_se2, b_se2, g2p);
  k4_proj<<<dim3(7, NB), 384, 0, stream>>>(d_s, g2p, w_proj_h, b_proj, x, out);
}